// Round 6
// baseline (322.327 us; speedup 1.0000x reference)
//
#include <hip/hip_runtime.h>
#include <hip/hip_bf16.h>

typedef __attribute__((ext_vector_type(8))) short short8;
typedef __attribute__((ext_vector_type(8))) unsigned short ushort8;
typedef __attribute__((ext_vector_type(4))) float f32x4;
typedef unsigned short ushort;

#define K_DIM 4096
#define N_DIM 4096
#define BK 64
#define NT (K_DIM / BK)   // 64 K-tiles

// ---------- numerics helpers (exactly mirror the reference) ----------

__device__ __forceinline__ float e4m3_rne(float v) {
    if (v >= 0.015625f) {
        unsigned u = __float_as_uint(v);
        unsigned lsb = (u >> 20) & 1u;
        u = (u + 0x7FFFFu + lsb) & 0xFFF00000u;
        return __uint_as_float(u);
    }
    return rintf(v * 512.0f) * 0.001953125f;
}

__device__ __forceinline__ float e2m1_level(float m) {
    float lv = 0.0f;
    lv = (m > 0.25f) ? 0.5f : lv;
    lv = (m > 0.75f) ? 1.0f : lv;
    lv = (m > 1.25f) ? 1.5f : lv;
    lv = (m > 1.75f) ? 2.0f : lv;
    lv = (m > 2.5f)  ? 3.0f : lv;
    lv = (m > 3.5f)  ? 4.0f : lv;
    lv = (m > 5.0f)  ? 6.0f : lv;
    return lv;
}

__device__ __forceinline__ ushort f32_to_bf16_bits(float f) {
    unsigned u = __float_as_uint(f);
    return (ushort)((u + 0x7FFFu + ((u >> 16) & 1u)) >> 16);
}

// ---------- small kernels ----------

__global__ void wamax_kernel(const float* __restrict__ w, unsigned* amax_bits, int n4) {
    float m = 0.f;
    const f32x4* w4 = (const f32x4*)w;
    for (int i = blockIdx.x * blockDim.x + threadIdx.x; i < n4; i += gridDim.x * blockDim.x) {
        f32x4 v = w4[i];
        m = fmaxf(m, fmaxf(fmaxf(fabsf(v.x), fabsf(v.y)), fmaxf(fabsf(v.z), fabsf(v.w))));
    }
#pragma unroll
    for (int off = 32; off >= 1; off >>= 1)
        m = fmaxf(m, __shfl_down(m, off));
    __shared__ float red[4];
    const int lane = threadIdx.x & 63, wv = threadIdx.x >> 6;
    if (lane == 0) red[wv] = m;
    __syncthreads();
    if (threadIdx.x == 0) {
        m = fmaxf(fmaxf(red[0], red[1]), fmaxf(red[2], red[3]));
        atomicMax(amax_bits, __float_as_uint(m));
    }
}

__global__ void quant16_kernel(const float* __restrict__ src,
                               const float* __restrict__ s2_ptr,
                               const unsigned* __restrict__ amax_bits,
                               ushort* __restrict__ dst, int nblk) {
    int t = blockIdx.x * blockDim.x + threadIdx.x;
    if (t >= nblk) return;
    float s2;
    if (s2_ptr) s2 = *s2_ptr;
    else        s2 = 2688.0f / __uint_as_float(*amax_bits);

    const f32x4* s = (const f32x4*)src + (size_t)t * 4;
    float vals[16];
    f32x4 v0 = s[0], v1 = s[1], v2 = s[2], v3 = s[3];
#pragma unroll
    for (int i = 0; i < 4; ++i) {
        vals[i] = v0[i]; vals[4 + i] = v1[i]; vals[8 + i] = v2[i]; vals[12 + i] = v3[i];
    }
    float amax = 0.f;
#pragma unroll
    for (int i = 0; i < 16; ++i) amax = fmaxf(amax, fabsf(vals[i]));

    float sf = e4m3_rne(fminf(amax * s2 / 6.0f, 448.0f));
    float scale = sf / s2;

    ushort8 o0, o1;
    if (scale > 0.f) {
#pragma unroll
        for (int i = 0; i < 16; ++i) {
            float r = vals[i] / scale;
            float m = fminf(fabsf(r), 6.0f);
            float q = copysignf(e2m1_level(m), r);
            ushort b = f32_to_bf16_bits(q * scale);
            if (i < 8) o0[i] = b; else o1[i - 8] = b;
        }
    } else {
#pragma unroll
        for (int i = 0; i < 8; ++i) { o0[i] = 0; o1[i] = 0; }
    }
    ushort8* d8 = (ushort8*)(dst + (size_t)t * 16);
    d8[0] = o0;
    d8[1] = o1;
}

// ---------- GEMM: C[M,N] = A[M,K]*B[N,K]^T + bias ----------
// 256x256 tile, BK=64, 8 waves, dbuf-2 LDS (128 KB), 4 quadrant-phases per
// K-tile with derived per-phase vmcnt (never drains <4 in steady state),
// dual mem-clobber barriers per phase, setprio around each MFMA cluster.
// Per-wave output: 64 rows from EACH A-half x 32 cols from EACH B-half, so
// each phase touches exactly one (A-half, B-half) pair -> per-half deadlines.

__device__ __forceinline__ void gload16(const ushort* g, ushort* l) {
    __builtin_amdgcn_global_load_lds(
        (const __attribute__((address_space(1))) void*)g,
        (__attribute__((address_space(3))) void*)l, 16, 0, 0);
}

#define VM4 asm volatile("s_waitcnt vmcnt(4)" ::: "memory")
#define VM2 asm volatile("s_waitcnt vmcnt(2)" ::: "memory")
#define VM0 asm volatile("s_waitcnt vmcnt(0)" ::: "memory")
#define BAR asm volatile("s_barrier" ::: "memory")

__global__ __launch_bounds__(512, 2) void gemm8(
    const ushort* __restrict__ Aq, const ushort* __restrict__ Bq,
    const float* __restrict__ bias, float* __restrict__ C) {
    // 2 bufs x { A:[2half][128][64], B:[2half][128][64] } bf16 = 128 KB
    __shared__ ushort lds[2 * 32768];

    const int tid  = threadIdx.x;
    const int lane = tid & 63;
    const int wave = tid >> 6;
    const int wr = wave >> 2;    // 0..1
    const int wc = wave & 3;     // 0..3

    // supertile swizzle: 256 consecutive ranks = 16(by) x 16(bx) region (64 MB set)
    const int swz = blockIdx.x;
    const int grp = swz >> 8, lcl = swz & 255;
    const int by = grp * 16 + (lcl & 15);
    const int bx = lcl >> 4;
    const int bm = by * 256, bn = bx * 256;

    // ---- staging: LDS linear in tid; global source pre-swizzled ----
    // within a [128][64] half: slot p (8 elem) of row r holds cg = (p - (r>>1)) & 7
    const int r0  = tid >> 3;                       // 0..63
    const int cg0 = ((tid & 7) - ((r0 >> 1) & 7)) & 7;
    const ushort* sA = Aq + (size_t)(bm + r0) * K_DIM + cg0 * 8;
    const ushort* sB = Bq + (size_t)(bn + r0) * K_DIM + cg0 * 8;
    ushort* dst0 = &lds[tid * 8];

    // ---- fragment read bases: p = (ks*4 + (lane>>4) + (row>>1)) & 7 ----
    const int rowA = wr * 64 + (lane & 15);
    const int rowB = wc * 32 + (lane & 15);
    const int ksl  = lane >> 4;
    const int baseA[2] = { rowA * 64 + ((((ksl) + (rowA >> 1)) & 7) << 3),
                           rowA * 64 + (((4 + ksl + (rowA >> 1)) & 7) << 3) };
    const int baseB[2] = { 16384 + rowB * 64 + ((((ksl) + (rowB >> 1)) & 7) << 3),
                           16384 + rowB * 64 + (((4 + ksl + (rowB >> 1)) & 7) << 3) };

    f32x4 acc[8][4];
#pragma unroll
    for (int m = 0; m < 8; ++m)
#pragma unroll
        for (int n = 0; n < 4; ++n) acc[m][n] = (f32x4)(0.f);

    short8 af[4][2], bfr[4][2];

// stage one half-tile (128 rows x 64 K) of tile t: 2 gloads
#define SA0(t) { const size_t ko = (size_t)(t) * BK; ushort* d = dst0 + ((t) & 1) * 32768;         \
    gload16(sA + ko, d); gload16(sA + (size_t)64 * K_DIM + ko, d + 4096); }
#define SA1(t) { const size_t ko = (size_t)(t) * BK; ushort* d = dst0 + ((t) & 1) * 32768 + 8192;  \
    gload16(sA + (size_t)128 * K_DIM + ko, d); gload16(sA + (size_t)192 * K_DIM + ko, d + 4096); }
#define SB0(t) { const size_t ko = (size_t)(t) * BK; ushort* d = dst0 + ((t) & 1) * 32768 + 16384; \
    gload16(sB + ko, d); gload16(sB + (size_t)64 * K_DIM + ko, d + 4096); }
#define SB1(t) { const size_t ko = (size_t)(t) * BK; ushort* d = dst0 + ((t) & 1) * 32768 + 24576; \
    gload16(sB + (size_t)128 * K_DIM + ko, d); gload16(sB + (size_t)192 * K_DIM + ko, d + 4096); }

#define READ_A(mh, Lb)                                                        \
    _Pragma("unroll") for (int m = 0; m < 4; ++m) {                           \
        af[m][0] = *(const short8*)((Lb) + (mh) * 8192 + m * 1024 + baseA[0]); \
        af[m][1] = *(const short8*)((Lb) + (mh) * 8192 + m * 1024 + baseA[1]); }
#define READ_B(nh, Lb)                                                        \
    _Pragma("unroll") for (int n = 0; n < 2; ++n) {                           \
        bfr[(nh)*2 + n][0] = *(const short8*)((Lb) + (nh) * 8192 + n * 1024 + baseB[0]); \
        bfr[(nh)*2 + n][1] = *(const short8*)((Lb) + (nh) * 8192 + n * 1024 + baseB[1]); }

// 16-MFMA quadrant: acc rows m0..m0+3 (af[0-3] regs), cols n0..n0+1
#define MM(m0, n0)                                                            \
    __builtin_amdgcn_s_setprio(1);                                            \
    _Pragma("unroll") for (int m = 0; m < 4; ++m)                             \
    _Pragma("unroll") for (int n = 0; n < 2; ++n)                             \
    _Pragma("unroll") for (int ks = 0; ks < 2; ++ks)                          \
        acc[(m0) + m][(n0) + n] = __builtin_amdgcn_mfma_f32_16x16x32_bf16(    \
            af[m][ks], bfr[(n0) + n][ks], acc[(m0) + m][(n0) + n], 0, 0, 0);  \
    __builtin_amdgcn_s_setprio(0);

    // prologue: stage tile 0 in deadline order (A0,B0 due first)
    SA0(0); SB0(0); SB1(0); SA1(0);
    VM4; BAR;                       // A0(0),B0(0) landed+published

#pragma unroll 1
    for (int t = 0; t < NT - 1; ++t) {
        const ushort* Lb = &lds[(t & 1) * 32768];
        // P1: quadrant (A-h0 x B-h0)
        READ_A(0, Lb); READ_B(0, Lb);
        SA0(t + 1);
        VM4; BAR;                   // covers B1(t)   [needed P2... publishes for P2-top]
        MM(0, 0);
        BAR;
        // P2: (A-h0 x B-h1)
        READ_B(1, Lb);
        SB0(t + 1);
        VM4; BAR;                   // covers A1(t)   [needed at P3-top]
        MM(0, 2);
        BAR;
        // P3: (A-h1 x B-h0)
        READ_A(1, Lb);
        SB1(t + 1);
        BAR;                        // P4-top reads nothing: no vmcnt
        MM(4, 0);
        BAR;
        // P4: (A-h1 x B-h1)
        SA1(t + 1);
        VM4; BAR;                   // covers A0(t+1),B0(t+1) [needed t+1.P1-top]
        MM(4, 2);
        BAR;
    }
    {   // tail tile t = NT-1: no staging; drain 2 -> 0
        const ushort* Lb = &lds[((NT - 1) & 1) * 32768];
        READ_A(0, Lb); READ_B(0, Lb);
        VM2; BAR;                   // B1 landed
        MM(0, 0);
        BAR;
        READ_B(1, Lb);
        VM0; BAR;                   // A1 landed
        MM(0, 2);
        BAR;
        READ_A(1, Lb);
        BAR;
        MM(4, 0);
        BAR;
        BAR;
        MM(4, 2);
        BAR;
    }

    // ---- epilogue: C/D layout col=lane&15, row=(lane>>4)*4+reg ----
    const int fq = lane >> 4, fr = lane & 15;
    const int colb = bn + wc * 32 + fr;
    float bv[4];
#pragma unroll
    for (int n = 0; n < 4; ++n) bv[n] = bias[colb + (n >> 1) * 128 + (n & 1) * 16];
#pragma unroll
    for (int m = 0; m < 8; ++m)
#pragma unroll
        for (int r = 0; r < 4; ++r) {
            const int row = bm + (m >> 2) * 128 + wr * 64 + (m & 3) * 16 + fq * 4 + r;
            float* Cr = C + (size_t)row * N_DIM + colb;
#pragma unroll
            for (int n = 0; n < 4; ++n)
                Cr[(n >> 1) * 128 + (n & 1) * 16] = acc[m][n][r] + bv[n];
        }
#undef SA0
#undef SA1
#undef SB0
#undef SB1
#undef READ_A
#undef READ_B
#undef MM
}

// ---------- launcher ----------

extern "C" void kernel_launch(void* const* d_in, const int* in_sizes, int n_in,
                              void* d_out, int out_size, void* d_ws, size_t ws_size,
                              hipStream_t stream) {
    const float* x     = (const float*)d_in[0];
    const float* w     = (const float*)d_in[1];
    const float* bias  = (const float*)d_in[2];
    const float* s_in2 = (const float*)d_in[3];
    float* out = (float*)d_out;

    const int M = in_sizes[0] / K_DIM;   // 8192

    unsigned* amax_bits = (unsigned*)d_ws;
    ushort* xq = (ushort*)((char*)d_ws + 256);
    ushort* wq = (ushort*)((char*)d_ws + 256 + (size_t)M * K_DIM * 2);

    hipMemsetAsync(amax_bits, 0, 4, stream);
    wamax_kernel<<<1024, 256, 0, stream>>>(w, amax_bits, (N_DIM * K_DIM) / 4);

    const int nblk_x = (M * K_DIM) / 16;
    quant16_kernel<<<nblk_x / 256, 256, 0, stream>>>(x, s_in2, nullptr, xq, nblk_x);
    const int nblk_w = (N_DIM * K_DIM) / 16;
    quant16_kernel<<<nblk_w / 256, 256, 0, stream>>>(w, nullptr, amax_bits, wq, nblk_w);

    const int nwg = (M / 256) * (N_DIM / 256);   // 512
    gemm8<<<nwg, 512, 0, stream>>>(xq, wq, bias, out);
}

// Round 7
// 298.605 us; speedup vs baseline: 1.0794x; 1.0794x over previous
//
#include <hip/hip_runtime.h>
#include <hip/hip_bf16.h>

typedef __attribute__((ext_vector_type(8))) short short8;
typedef __attribute__((ext_vector_type(8))) unsigned short ushort8;
typedef __attribute__((ext_vector_type(4))) float f32x4;
typedef unsigned short ushort;

#define K_DIM 4096
#define N_DIM 4096
#define BK 64
#define NT (K_DIM / BK)   // 64 K-tiles

// ---------- numerics helpers (exactly mirror the reference) ----------

__device__ __forceinline__ float e4m3_rne(float v) {
    if (v >= 0.015625f) {
        unsigned u = __float_as_uint(v);
        unsigned lsb = (u >> 20) & 1u;
        u = (u + 0x7FFFFu + lsb) & 0xFFF00000u;
        return __uint_as_float(u);
    }
    return rintf(v * 512.0f) * 0.001953125f;
}

__device__ __forceinline__ float e2m1_level(float m) {
    float lv = 0.0f;
    lv = (m > 0.25f) ? 0.5f : lv;
    lv = (m > 0.75f) ? 1.0f : lv;
    lv = (m > 1.25f) ? 1.5f : lv;
    lv = (m > 1.75f) ? 2.0f : lv;
    lv = (m > 2.5f)  ? 3.0f : lv;
    lv = (m > 3.5f)  ? 4.0f : lv;
    lv = (m > 5.0f)  ? 6.0f : lv;
    return lv;
}

__device__ __forceinline__ ushort f32_to_bf16_bits(float f) {
    unsigned u = __float_as_uint(f);
    return (ushort)((u + 0x7FFFu + ((u >> 16) & 1u)) >> 16);
}

// ---------- small kernels ----------

__global__ void wamax_kernel(const float* __restrict__ w, unsigned* amax_bits, int n4) {
    float m = 0.f;
    const f32x4* w4 = (const f32x4*)w;
    for (int i = blockIdx.x * blockDim.x + threadIdx.x; i < n4; i += gridDim.x * blockDim.x) {
        f32x4 v = w4[i];
        m = fmaxf(m, fmaxf(fmaxf(fabsf(v.x), fabsf(v.y)), fmaxf(fabsf(v.z), fabsf(v.w))));
    }
#pragma unroll
    for (int off = 32; off >= 1; off >>= 1)
        m = fmaxf(m, __shfl_down(m, off));
    __shared__ float red[4];
    const int lane = threadIdx.x & 63, wv = threadIdx.x >> 6;
    if (lane == 0) red[wv] = m;
    __syncthreads();
    if (threadIdx.x == 0) {
        m = fmaxf(fmaxf(red[0], red[1]), fmaxf(red[2], red[3]));
        atomicMax(amax_bits, __float_as_uint(m));
    }
}

__global__ void quant16_kernel(const float* __restrict__ src,
                               const float* __restrict__ s2_ptr,
                               const unsigned* __restrict__ amax_bits,
                               ushort* __restrict__ dst, int nblk) {
    int t = blockIdx.x * blockDim.x + threadIdx.x;
    if (t >= nblk) return;
    float s2;
    if (s2_ptr) s2 = *s2_ptr;
    else        s2 = 2688.0f / __uint_as_float(*amax_bits);

    const f32x4* s = (const f32x4*)src + (size_t)t * 4;
    float vals[16];
    f32x4 v0 = s[0], v1 = s[1], v2 = s[2], v3 = s[3];
#pragma unroll
    for (int i = 0; i < 4; ++i) {
        vals[i] = v0[i]; vals[4 + i] = v1[i]; vals[8 + i] = v2[i]; vals[12 + i] = v3[i];
    }
    float amax = 0.f;
#pragma unroll
    for (int i = 0; i < 16; ++i) amax = fmaxf(amax, fabsf(vals[i]));

    float sf = e4m3_rne(fminf(amax * s2 / 6.0f, 448.0f));
    float scale = sf / s2;

    ushort8 o0, o1;
    if (scale > 0.f) {
#pragma unroll
        for (int i = 0; i < 16; ++i) {
            float r = vals[i] / scale;
            float m = fminf(fabsf(r), 6.0f);
            float q = copysignf(e2m1_level(m), r);
            ushort b = f32_to_bf16_bits(q * scale);
            if (i < 8) o0[i] = b; else o1[i - 8] = b;
        }
    } else {
#pragma unroll
        for (int i = 0; i < 8; ++i) { o0[i] = 0; o1[i] = 0; }
    }
    ushort8* d8 = (ushort8*)(dst + (size_t)t * 16);
    d8[0] = o0;
    d8[1] = o1;
}

// ---------- GEMM: C[M,N] = A[M,K]*B[N,K]^T + bias ----------
// 256x256 tile, BK=64, 8 waves, dbuf-2 LDS (128 KB), 4 quadrant-phases per
// K-tile, derived vmcnt(4), dual barriers, setprio (R6 structure).
// FIXED swizzle: p = (kslot + row) & 7 -- row stride is 128 B = 32 banks, so
// bank depends ONLY on p; full-rank p over any 8 consecutive rows makes each
// 8-lane LDS pass hit all 32 banks (R6's row>>1 gave 2-way per pass, 2.5e7).

__device__ __forceinline__ void gload16(const ushort* g, ushort* l) {
    __builtin_amdgcn_global_load_lds(
        (const __attribute__((address_space(1))) void*)g,
        (__attribute__((address_space(3))) void*)l, 16, 0, 0);
}

#define VM4 asm volatile("s_waitcnt vmcnt(4)" ::: "memory")
#define VM2 asm volatile("s_waitcnt vmcnt(2)" ::: "memory")
#define VM0 asm volatile("s_waitcnt vmcnt(0)" ::: "memory")
#define BAR asm volatile("s_barrier" ::: "memory")

__global__ __launch_bounds__(512, 2) void gemm8(
    const ushort* __restrict__ Aq, const ushort* __restrict__ Bq,
    const float* __restrict__ bias, float* __restrict__ C) {
    // 2 bufs x { A:[2half][128][64], B:[2half][128][64] } bf16 = 128 KB
    __shared__ ushort lds[2 * 32768];

    const int tid  = threadIdx.x;
    const int lane = tid & 63;
    const int wave = tid >> 6;
    const int wr = wave >> 2;    // 0..1
    const int wc = wave & 3;     // 0..3

    // supertile swizzle: 256 consecutive ranks = 16(by) x 16(bx) region (64 MB set)
    const int swz = blockIdx.x;
    const int grp = swz >> 8, lcl = swz & 255;
    const int by = grp * 16 + (lcl & 15);
    const int bx = lcl >> 4;
    const int bm = by * 256, bn = bx * 256;

    // ---- staging: LDS linear in tid; global source pre-swizzled ----
    // slot p of row r holds k-group cg = (p - r) & 7
    const int r0  = tid >> 3;                       // 0..63
    const int cg0 = ((tid & 7) - r0) & 7;
    const ushort* sA = Aq + (size_t)(bm + r0) * K_DIM + cg0 * 8;
    const ushort* sB = Bq + (size_t)(bn + r0) * K_DIM + cg0 * 8;
    ushort* dst0 = &lds[tid * 8];

    // ---- fragment read bases: kslot q lives at p = (q + row) & 7 ----
    const int rowA = wr * 64 + (lane & 15);
    const int rowB = wc * 32 + (lane & 15);
    const int ksl  = lane >> 4;
    const int baseA[2] = { rowA * 64 + ((((ksl) + rowA) & 7) << 3),
                           rowA * 64 + (((4 + ksl + rowA) & 7) << 3) };
    const int baseB[2] = { 16384 + rowB * 64 + ((((ksl) + rowB) & 7) << 3),
                           16384 + rowB * 64 + (((4 + ksl + rowB) & 7) << 3) };

    f32x4 acc[8][4];
#pragma unroll
    for (int m = 0; m < 8; ++m)
#pragma unroll
        for (int n = 0; n < 4; ++n) acc[m][n] = (f32x4)(0.f);

    short8 af[4][2], bfr[4][2];

// stage one half-tile (128 rows x 64 K) of tile t: 2 gloads
#define SA0(t) { const size_t ko = (size_t)(t) * BK; ushort* d = dst0 + ((t) & 1) * 32768;         \
    gload16(sA + ko, d); gload16(sA + (size_t)64 * K_DIM + ko, d + 4096); }
#define SA1(t) { const size_t ko = (size_t)(t) * BK; ushort* d = dst0 + ((t) & 1) * 32768 + 8192;  \
    gload16(sA + (size_t)128 * K_DIM + ko, d); gload16(sA + (size_t)192 * K_DIM + ko, d + 4096); }
#define SB0(t) { const size_t ko = (size_t)(t) * BK; ushort* d = dst0 + ((t) & 1) * 32768 + 16384; \
    gload16(sB + ko, d); gload16(sB + (size_t)64 * K_DIM + ko, d + 4096); }
#define SB1(t) { const size_t ko = (size_t)(t) * BK; ushort* d = dst0 + ((t) & 1) * 32768 + 24576; \
    gload16(sB + (size_t)128 * K_DIM + ko, d); gload16(sB + (size_t)192 * K_DIM + ko, d + 4096); }

#define READ_A(mh, Lb)                                                        \
    _Pragma("unroll") for (int m = 0; m < 4; ++m) {                           \
        af[m][0] = *(const short8*)((Lb) + (mh) * 8192 + m * 1024 + baseA[0]); \
        af[m][1] = *(const short8*)((Lb) + (mh) * 8192 + m * 1024 + baseA[1]); }
#define READ_B(nh, Lb)                                                        \
    _Pragma("unroll") for (int n = 0; n < 2; ++n) {                           \
        bfr[(nh)*2 + n][0] = *(const short8*)((Lb) + (nh) * 8192 + n * 1024 + baseB[0]); \
        bfr[(nh)*2 + n][1] = *(const short8*)((Lb) + (nh) * 8192 + n * 1024 + baseB[1]); }

// 16-MFMA quadrant: acc rows m0..m0+3 (af[0-3] regs), cols n0..n0+1
#define MM(m0, n0)                                                            \
    __builtin_amdgcn_s_setprio(1);                                            \
    _Pragma("unroll") for (int m = 0; m < 4; ++m)                             \
    _Pragma("unroll") for (int n = 0; n < 2; ++n)                             \
    _Pragma("unroll") for (int ks = 0; ks < 2; ++ks)                          \
        acc[(m0) + m][(n0) + n] = __builtin_amdgcn_mfma_f32_16x16x32_bf16(    \
            af[m][ks], bfr[(n0) + n][ks], acc[(m0) + m][(n0) + n], 0, 0, 0);  \
    __builtin_amdgcn_s_setprio(0);

    // prologue: stage tile 0 in deadline order (A0,B0 due first)
    SA0(0); SB0(0); SB1(0); SA1(0);
    VM4; BAR;                       // A0(0),B0(0) landed+published

#pragma unroll 1
    for (int t = 0; t < NT - 1; ++t) {
        const ushort* Lb = &lds[(t & 1) * 32768];
        // P1: quadrant (A-h0 x B-h0)
        READ_A(0, Lb); READ_B(0, Lb);
        SA0(t + 1);
        VM4; BAR;                   // covers B1(t)  [needed at P2-top]
        MM(0, 0);
        BAR;
        // P2: (A-h0 x B-h1)
        READ_B(1, Lb);
        SB0(t + 1);
        VM4; BAR;                   // covers A1(t)  [needed at P3-top]
        MM(0, 2);
        BAR;
        // P3: (A-h1 x B-h0)
        READ_A(1, Lb);
        SB1(t + 1);
        BAR;                        // P4-top reads nothing: no vmcnt
        MM(4, 0);
        BAR;
        // P4: (A-h1 x B-h1)
        SA1(t + 1);
        VM4; BAR;                   // covers A0(t+1),B0(t+1) [needed t+1.P1-top]
        MM(4, 2);
        BAR;
    }
    {   // tail tile t = NT-1: no staging; drain 2 -> 0
        const ushort* Lb = &lds[((NT - 1) & 1) * 32768];
        READ_A(0, Lb); READ_B(0, Lb);
        VM2; BAR;                   // B1 landed
        MM(0, 0);
        BAR;
        READ_B(1, Lb);
        VM0; BAR;                   // A1 landed
        MM(0, 2);
        BAR;
        READ_A(1, Lb);
        BAR;
        MM(4, 0);
        BAR;
        BAR;
        MM(4, 2);
        BAR;
    }

    // ---- epilogue: C/D layout col=lane&15, row=(lane>>4)*4+reg ----
    const int fq = lane >> 4, fr = lane & 15;
    const int colb = bn + wc * 32 + fr;
    float bv[4];
#pragma unroll
    for (int n = 0; n < 4; ++n) bv[n] = bias[colb + (n >> 1) * 128 + (n & 1) * 16];
#pragma unroll
    for (int m = 0; m < 8; ++m)
#pragma unroll
        for (int r = 0; r < 4; ++r) {
            const int row = bm + (m >> 2) * 128 + wr * 64 + (m & 3) * 16 + fq * 4 + r;
            float* Cr = C + (size_t)row * N_DIM + colb;
#pragma unroll
            for (int n = 0; n < 4; ++n)
                Cr[(n >> 1) * 128 + (n & 1) * 16] = acc[m][n][r] + bv[n];
        }
#undef SA0
#undef SA1
#undef SB0
#undef SB1
#undef READ_A
#undef READ_B
#undef MM
}

// ---------- launcher ----------

extern "C" void kernel_launch(void* const* d_in, const int* in_sizes, int n_in,
                              void* d_out, int out_size, void* d_ws, size_t ws_size,
                              hipStream_t stream) {
    const float* x     = (const float*)d_in[0];
    const float* w     = (const float*)d_in[1];
    const float* bias  = (const float*)d_in[2];
    const float* s_in2 = (const float*)d_in[3];
    float* out = (float*)d_out;

    const int M = in_sizes[0] / K_DIM;   // 8192

    unsigned* amax_bits = (unsigned*)d_ws;
    ushort* xq = (ushort*)((char*)d_ws + 256);
    ushort* wq = (ushort*)((char*)d_ws + 256 + (size_t)M * K_DIM * 2);

    hipMemsetAsync(amax_bits, 0, 4, stream);
    wamax_kernel<<<1024, 256, 0, stream>>>(w, amax_bits, (N_DIM * K_DIM) / 4);

    const int nblk_x = (M * K_DIM) / 16;
    quant16_kernel<<<nblk_x / 256, 256, 0, stream>>>(x, s_in2, nullptr, xq, nblk_x);
    const int nblk_w = (N_DIM * K_DIM) / 16;
    quant16_kernel<<<nblk_w / 256, 256, 0, stream>>>(w, nullptr, amax_bits, wq, nblk_w);

    const int nwg = (M / 256) * (N_DIM / 256);   // 512
    gemm8<<<nwg, 512, 0, stream>>>(xq, wq, bias, out);
}

// Round 8
// 289.176 us; speedup vs baseline: 1.1146x; 1.0326x over previous
//
#include <hip/hip_runtime.h>
#include <hip/hip_bf16.h>

typedef __attribute__((ext_vector_type(8))) short short8;
typedef __attribute__((ext_vector_type(8))) unsigned short ushort8;
typedef __attribute__((ext_vector_type(4))) float f32x4;
typedef unsigned short ushort;

#define K_DIM 4096
#define N_DIM 4096
#define BK 64
#define NT (K_DIM / BK)   // 64 K-tiles

// ---------- numerics helpers (exactly mirror the reference) ----------

__device__ __forceinline__ float e4m3_rne(float v) {
    if (v >= 0.015625f) {
        unsigned u = __float_as_uint(v);
        unsigned lsb = (u >> 20) & 1u;
        u = (u + 0x7FFFFu + lsb) & 0xFFF00000u;
        return __uint_as_float(u);
    }
    return rintf(v * 512.0f) * 0.001953125f;
}

__device__ __forceinline__ float e2m1_level(float m) {
    float lv = 0.0f;
    lv = (m > 0.25f) ? 0.5f : lv;
    lv = (m > 0.75f) ? 1.0f : lv;
    lv = (m > 1.25f) ? 1.5f : lv;
    lv = (m > 1.75f) ? 2.0f : lv;
    lv = (m > 2.5f)  ? 3.0f : lv;
    lv = (m > 3.5f)  ? 4.0f : lv;
    lv = (m > 5.0f)  ? 6.0f : lv;
    return lv;
}

__device__ __forceinline__ ushort f32_to_bf16_bits(float f) {
    unsigned u = __float_as_uint(f);
    return (ushort)((u + 0x7FFFu + ((u >> 16) & 1u)) >> 16);
}

// ---------- small kernels ----------

__global__ void wamax_kernel(const float* __restrict__ w, unsigned* amax_bits, int n4) {
    float m = 0.f;
    const f32x4* w4 = (const f32x4*)w;
    for (int i = blockIdx.x * blockDim.x + threadIdx.x; i < n4; i += gridDim.x * blockDim.x) {
        f32x4 v = w4[i];
        m = fmaxf(m, fmaxf(fmaxf(fabsf(v.x), fabsf(v.y)), fmaxf(fabsf(v.z), fabsf(v.w))));
    }
#pragma unroll
    for (int off = 32; off >= 1; off >>= 1)
        m = fmaxf(m, __shfl_down(m, off));
    __shared__ float red[4];
    const int lane = threadIdx.x & 63, wv = threadIdx.x >> 6;
    if (lane == 0) red[wv] = m;
    __syncthreads();
    if (threadIdx.x == 0) {
        m = fmaxf(fmaxf(red[0], red[1]), fmaxf(red[2], red[3]));
        atomicMax(amax_bits, __float_as_uint(m));
    }
}

__global__ void quant16_kernel(const float* __restrict__ src,
                               const float* __restrict__ s2_ptr,
                               const unsigned* __restrict__ amax_bits,
                               ushort* __restrict__ dst, int nblk) {
    int t = blockIdx.x * blockDim.x + threadIdx.x;
    if (t >= nblk) return;
    float s2;
    if (s2_ptr) s2 = *s2_ptr;
    else        s2 = 2688.0f / __uint_as_float(*amax_bits);

    const f32x4* s = (const f32x4*)src + (size_t)t * 4;
    float vals[16];
    f32x4 v0 = s[0], v1 = s[1], v2 = s[2], v3 = s[3];
#pragma unroll
    for (int i = 0; i < 4; ++i) {
        vals[i] = v0[i]; vals[4 + i] = v1[i]; vals[8 + i] = v2[i]; vals[12 + i] = v3[i];
    }
    float amax = 0.f;
#pragma unroll
    for (int i = 0; i < 16; ++i) amax = fmaxf(amax, fabsf(vals[i]));

    float sf = e4m3_rne(fminf(amax * s2 / 6.0f, 448.0f));
    float scale = sf / s2;

    ushort8 o0, o1;
    if (scale > 0.f) {
#pragma unroll
        for (int i = 0; i < 16; ++i) {
            float r = vals[i] / scale;
            float m = fminf(fabsf(r), 6.0f);
            float q = copysignf(e2m1_level(m), r);
            ushort b = f32_to_bf16_bits(q * scale);
            if (i < 8) o0[i] = b; else o1[i - 8] = b;
        }
    } else {
#pragma unroll
        for (int i = 0; i < 8; ++i) { o0[i] = 0; o1[i] = 0; }
    }
    ushort8* d8 = (ushort8*)(dst + (size_t)t * 16);
    d8[0] = o0;
    d8[1] = o1;
}

// ---------- GEMM: C[M,N] = A[M,K]*B[N,K]^T + bias ----------
// 256x256 tile, BK=64, 8 waves, dbuf-2 LDS (128 KB).
// Software-pipelined quadrant phases: ds_reads for quadrant q+1 are issued
// BEFORE quadrant q's MFMA cluster with a COUNTED lgkmcnt wait, so the LDS
// pipe serves the next quadrant while the matrix pipe runs the current one.
// Swizzle: slot p of row r holds k-group (p-r)&7 (proven 0-conflict in R7).

__device__ __forceinline__ void gload16(const ushort* g, ushort* l) {
    __builtin_amdgcn_global_load_lds(
        (const __attribute__((address_space(1))) void*)g,
        (__attribute__((address_space(3))) void*)l, 16, 0, 0);
}

#define VM4 asm volatile("s_waitcnt vmcnt(4)" ::: "memory")
#define VM2 asm volatile("s_waitcnt vmcnt(2)" ::: "memory")
#define VM0 asm volatile("s_waitcnt vmcnt(0)" ::: "memory")
#define LG4 asm volatile("s_waitcnt lgkmcnt(4)" ::: "memory")
#define LG8 asm volatile("s_waitcnt lgkmcnt(8)" ::: "memory")
#define LG0 asm volatile("s_waitcnt lgkmcnt(0)" ::: "memory")
#define BAR asm volatile("s_barrier" ::: "memory")

__global__ __launch_bounds__(512, 2) void gemm8(
    const ushort* __restrict__ Aq, const ushort* __restrict__ Bq,
    const float* __restrict__ bias, float* __restrict__ C) {
    // 2 bufs x { A:[2half][128][64], B:[2half][128][64] } bf16 = 128 KB
    __shared__ ushort lds[2 * 32768];

    const int tid  = threadIdx.x;
    const int lane = tid & 63;
    const int wave = tid >> 6;
    const int wr = wave >> 2;    // 0..1
    const int wc = wave & 3;     // 0..3

    // supertile swizzle: 256 consecutive ranks = 16(by) x 16(bx) region (64 MB set)
    const int swz = blockIdx.x;
    const int grp = swz >> 8, lcl = swz & 255;
    const int by = grp * 16 + (lcl & 15);
    const int bx = lcl >> 4;
    const int bm = by * 256, bn = bx * 256;

    // ---- staging: LDS linear in tid; global source pre-swizzled ----
    // slot p of row r holds k-group cg = (p - r) & 7
    const int r0  = tid >> 3;                       // 0..63
    const int cg0 = ((tid & 7) - r0) & 7;
    const ushort* sA = Aq + (size_t)(bm + r0) * K_DIM + cg0 * 8;
    const ushort* sB = Bq + (size_t)(bn + r0) * K_DIM + cg0 * 8;
    ushort* dst0 = &lds[tid * 8];

    // ---- fragment read bases: kslot q lives at p = (q + row) & 7 ----
    const int rowA = wr * 64 + (lane & 15);
    const int rowB = wc * 32 + (lane & 15);
    const int ksl  = lane >> 4;
    const int baseA[2] = { rowA * 64 + ((((ksl) + rowA) & 7) << 3),
                           rowA * 64 + (((4 + ksl + rowA) & 7) << 3) };
    const int baseB[2] = { rowB * 64 + ((((ksl) + rowB) & 7) << 3),
                           rowB * 64 + (((4 + ksl + rowB) & 7) << 3) };

    f32x4 acc[8][4];
#pragma unroll
    for (int m = 0; m < 8; ++m)
#pragma unroll
        for (int n = 0; n < 4; ++n) acc[m][n] = (f32x4)(0.f);

    // double-buffered fragment registers (static names -> no WAR stalls)
    short8 aLo[4][2], aHi[4][2], bLo[2][2], bHi[2][2];

// stage one half-tile (128 rows x 64 K) of tile t: 2 gloads
#define SA0(t) { const size_t ko = (size_t)(t) * BK; ushort* d = dst0 + ((t) & 1) * 32768;         \
    gload16(sA + ko, d); gload16(sA + (size_t)64 * K_DIM + ko, d + 4096); }
#define SA1(t) { const size_t ko = (size_t)(t) * BK; ushort* d = dst0 + ((t) & 1) * 32768 + 8192;  \
    gload16(sA + (size_t)128 * K_DIM + ko, d); gload16(sA + (size_t)192 * K_DIM + ko, d + 4096); }
#define SB0(t) { const size_t ko = (size_t)(t) * BK; ushort* d = dst0 + ((t) & 1) * 32768 + 16384; \
    gload16(sB + ko, d); gload16(sB + (size_t)64 * K_DIM + ko, d + 4096); }
#define SB1(t) { const size_t ko = (size_t)(t) * BK; ushort* d = dst0 + ((t) & 1) * 32768 + 24576; \
    gload16(sB + (size_t)128 * K_DIM + ko, d); gload16(sB + (size_t)192 * K_DIM + ko, d + 4096); }

// region offsets within a buffer: A0=0, A1=8192, B0=16384, B1=24576
#define READ_ALO(Lb) _Pragma("unroll") for (int m = 0; m < 4; ++m) {          \
        aLo[m][0] = *(const short8*)((Lb) + m * 1024 + baseA[0]);             \
        aLo[m][1] = *(const short8*)((Lb) + m * 1024 + baseA[1]); }
#define READ_AHI(Lb) _Pragma("unroll") for (int m = 0; m < 4; ++m) {          \
        aHi[m][0] = *(const short8*)((Lb) + 8192 + m * 1024 + baseA[0]);      \
        aHi[m][1] = *(const short8*)((Lb) + 8192 + m * 1024 + baseA[1]); }
#define READ_BLO(Lb) _Pragma("unroll") for (int n = 0; n < 2; ++n) {          \
        bLo[n][0] = *(const short8*)((Lb) + 16384 + n * 1024 + baseB[0]);     \
        bLo[n][1] = *(const short8*)((Lb) + 16384 + n * 1024 + baseB[1]); }
#define READ_BHI(Lb) _Pragma("unroll") for (int n = 0; n < 2; ++n) {          \
        bHi[n][0] = *(const short8*)((Lb) + 24576 + n * 1024 + baseB[0]);     \
        bHi[n][1] = *(const short8*)((Lb) + 24576 + n * 1024 + baseB[1]); }

#define MMQ(AF, BF, MO, NO)                                                   \
    __builtin_amdgcn_s_setprio(1);                                            \
    _Pragma("unroll") for (int m = 0; m < 4; ++m)                             \
    _Pragma("unroll") for (int n = 0; n < 2; ++n)                             \
    _Pragma("unroll") for (int ks = 0; ks < 2; ++ks)                          \
        acc[(MO) + m][(NO) + n] = __builtin_amdgcn_mfma_f32_16x16x32_bf16(    \
            AF[m][ks], BF[n][ks], acc[(MO) + m][(NO) + n], 0, 0, 0);          \
    __builtin_amdgcn_s_setprio(0);

    // prologue: stage tile 0; publish A0,B0; issue Q1(0) reads
    SA0(0); SB0(0); SB1(0); SA1(0);
    VM4; BAR;                           // A0(0),B0(0) landed; SB1,SA1 flying
    {
        const ushort* L0 = &lds[0];
        READ_ALO(L0); READ_BLO(L0);     // 12 reads for Q1(0)
    }

#pragma unroll 1
    for (int t = 0; t < NT - 1; ++t) {
        const ushort* Lb = &lds[(t & 1) * 32768];
        const ushort* Ln = &lds[((t + 1) & 1) * 32768];
        // Phase A: issue Q2 reads, MFMA Q1 (reads from prev phase D / prologue)
        VM2; BAR;                       // SB1(t) landed+published
        READ_BHI(Lb);                   // 4 reads (Q2)
        SA0(t + 1);
        LG4;                            // Q1's 12 reads done; 4 in flight
        MMQ(aLo, bLo, 0, 0);
        // Phase B: issue Q3 reads, MFMA Q2
        VM2; BAR;                       // SA1(t) landed+published
        READ_AHI(Lb);                   // 8 reads (Q3)
        SB0(t + 1);
        LG8;                            // Q2's 4 reads done; 8 in flight
        MMQ(aLo, bHi, 0, 2);
        // Phase C: MFMA Q3 (no new reads)
        SB1(t + 1);
        LG0;                            // Q3's 8 reads done
        MMQ(aHi, bLo, 4, 0);
        // Phase D: issue Q1(t+1) reads, MFMA Q4
        VM2; BAR;                       // SA0(t+1),SB0(t+1) landed+published
        READ_ALO(Ln); READ_BLO(Ln);     // 12 reads (Q1 of t+1)
        SA1(t + 1);
        MMQ(aHi, bHi, 4, 2);            // operands ready since phase B/C
    }
    {   // tail tile t = NT-1 (no staging)
        const ushort* Lb = &lds[((NT - 1) & 1) * 32768];
        VM2; BAR;                       // SB1(T) landed
        READ_BHI(Lb);
        LG4;
        MMQ(aLo, bLo, 0, 0);
        VM0; BAR;                       // SA1(T) landed
        READ_AHI(Lb);
        LG8;
        MMQ(aLo, bHi, 0, 2);
        LG0;
        MMQ(aHi, bLo, 4, 0);
        MMQ(aHi, bHi, 4, 2);
    }

    // ---- epilogue: C/D layout col=lane&15, row=(lane>>4)*4+reg ----
    const int fq = lane >> 4, fr = lane & 15;
    const int colb = bn + wc * 32 + fr;
    float bv[4];
#pragma unroll
    for (int n = 0; n < 4; ++n) bv[n] = bias[colb + (n >> 1) * 128 + (n & 1) * 16];
#pragma unroll
    for (int m = 0; m < 8; ++m)
#pragma unroll
        for (int r = 0; r < 4; ++r) {
            const int row = bm + (m >> 2) * 128 + wr * 64 + (m & 3) * 16 + fq * 4 + r;
            float* Cr = C + (size_t)row * N_DIM + colb;
#pragma unroll
            for (int n = 0; n < 4; ++n)
                Cr[(n >> 1) * 128 + (n & 1) * 16] = acc[m][n][r] + bv[n];
        }
#undef SA0
#undef SA1
#undef SB0
#undef SB1
#undef READ_ALO
#undef READ_AHI
#undef READ_BLO
#undef READ_BHI
#undef MMQ
}

// ---------- launcher ----------

extern "C" void kernel_launch(void* const* d_in, const int* in_sizes, int n_in,
                              void* d_out, int out_size, void* d_ws, size_t ws_size,
                              hipStream_t stream) {
    const float* x     = (const float*)d_in[0];
    const float* w     = (const float*)d_in[1];
    const float* bias  = (const float*)d_in[2];
    const float* s_in2 = (const float*)d_in[3];
    float* out = (float*)d_out;

    const int M = in_sizes[0] / K_DIM;   // 8192

    unsigned* amax_bits = (unsigned*)d_ws;
    ushort* xq = (ushort*)((char*)d_ws + 256);
    ushort* wq = (ushort*)((char*)d_ws + 256 + (size_t)M * K_DIM * 2);

    hipMemsetAsync(amax_bits, 0, 4, stream);
    wamax_kernel<<<1024, 256, 0, stream>>>(w, amax_bits, (N_DIM * K_DIM) / 4);

    const int nblk_x = (M * K_DIM) / 16;
    quant16_kernel<<<nblk_x / 256, 256, 0, stream>>>(x, s_in2, nullptr, xq, nblk_x);
    const int nblk_w = (N_DIM * K_DIM) / 16;
    quant16_kernel<<<nblk_w / 256, 256, 0, stream>>>(w, nullptr, amax_bits, wq, nblk_w);

    const int nwg = (M / 256) * (N_DIM / 256);   // 512
    gemm8<<<nwg, 512, 0, stream>>>(xq, wq, bias, out);
}